// Round 15
// baseline (2343.937 us; speedup 1.0000x reference)
//
#include <hip/hip_runtime.h>
#include <math.h>

// Center-tracking f32 SNN: reductions in f64 (rounded once to f32 at the
// reference's materialization points), elementwise chains in exact-order f32
// round-to-nearest ops (no FMA), constants as f32 values.
// R15: layer-per-kernel with internal t-loop; LIF/axon states in REGISTERS
// (init 0); activations streamed via per-t workspace planes. 9 dispatches.
// SGPR f64 weights for convs.

__device__ __forceinline__ float axon_step(float A1, float A2, float y1, float y2, float x) {
    return __fadd_rn(__fadd_rn(__fmul_rn(A1, y1), __fmul_rn(A2, y2)), x);
}

__global__ void diag_kernel(float* out, float v, int n) {
    int i = blockIdx.x * 256 + threadIdx.x;
    if (i < n) out[i] = v;
}

__global__ void canary_kernel(float* out, int n) {
    __shared__ float ssum[256];
    float s = 0.f;
    for (int i = threadIdx.x; i < n; i += 256) s += out[i];
    ssum[threadIdx.x] = s;
    __syncthreads();
    for (int k = 128; k > 0; k >>= 1) {
        if (threadIdx.x < k) ssum[threadIdx.x] += ssum[threadIdx.x + k];
        __syncthreads();
    }
    if (threadIdx.x == 0 && ssum[0] == 0.0f) out[0] = 444.0f;
}

// ---- one-time: weights f32 -> f64 (exact) ----
__global__ __launch_bounds__(256) void wcvt_kernel(
        const float* __restrict__ w2, const float* __restrict__ w3,
        const float* __restrict__ w5,
        double* __restrict__ w2d, double* __restrict__ w3d,
        double* __restrict__ w5d) {
    int i = blockIdx.x * 256 + threadIdx.x;
    if (i < 9216)  w2d[i] = (double)w2[i];
    if (i < 18432) w3d[i] = (double)w3[i];
    if (i < 36864) w5d[i] = (double)w5[i];
}

// ---- ann1: frame = sigmoid(conv+b), once ----
__global__ __launch_bounds__(256) void ann1_kernel(
        const float* __restrict__ in, const float* __restrict__ w,
        const float* __restrict__ bias, float* __restrict__ frame) {
    int bid = blockIdx.x;
    int b = bid & 31, co = bid >> 5;
    int tid = threadIdx.x;
    __shared__ double wsh[27];
    if (tid < 27) wsh[tid] = (double)w[co * 27 + tid];
    __syncthreads();
    float bb = bias[co];
    for (int p = tid; p < 900; p += 256) {
        int y = p / 30, x = p % 30;
        double acc = 0.0;
        #pragma unroll
        for (int ci = 0; ci < 3; ++ci) {
            const float* r = in + ((b * 3 + ci) * 32 + y) * 32 + x;
            const double* wp = wsh + ci * 9;
            #pragma unroll
            for (int ky = 0; ky < 3; ++ky)
                acc += (double)r[ky*32+0]*wp[ky*3+0] + (double)r[ky*32+1]*wp[ky*3+1]
                     + (double)r[ky*32+2]*wp[ky*3+2];
        }
        float z = __fadd_rn((float)acc, bb);
        frame[((b * 32 + co) * 30 + y) * 30 + x] =
            (float)(1.0 / (1.0 + exp(-(double)z)));
    }
}

// ---- axon2g: 25-step exact-order f32 IIR in registers -> a2ch[25] ----
__global__ __launch_bounds__(256) void axon2g_kernel(
        const float2* __restrict__ frame2, float* __restrict__ a2ch,
        float A1, float A2) {
    int g = blockIdx.x * 256 + threadIdx.x;  // 460800 exact
    float2 f = frame2[g];
    float y1a = 0.f, y2a = 0.f, y1b = 0.f, y2b = 0.f;
    #pragma unroll
    for (int k = 0; k < 25; ++k) {
        float v0 = axon_step(A1, A2, y1a, y2a, f.x);
        float v1 = axon_step(A1, A2, y1b, y2b, f.y);
        ((float2*)(a2ch + (size_t)k * 921600))[g] = make_float2(v0, v1);
        y2a = y1a; y1a = v0;
        y2b = y1b; y1b = v1;
    }
}

// ---- conv2g: all-t conv2+b2+LIF2+axon3 -> a3ch[25] ; reg states ----
// grid: b(32) x cop(16) x sp(2) = 1024 blocks, 256 thr (196 active); no LDS
__global__ __launch_bounds__(256) void conv2g_kernel(
        const float* __restrict__ a2ch, const double* __restrict__ w2d,
        const float* __restrict__ b2, float* __restrict__ a3ch,
        float A1, float A2, float eta_m) {
    int bid = blockIdx.x;
    int b = bid & 31, cop = (bid >> 5) & 15, sp = (bid >> 9) & 1;
    int co0 = cop * 2;
    int row0 = sp * 14;
    int p = threadIdx.x;
    if (p >= 196) return;
    int lr = p / 14, xp = p % 14;
    int y = row0 + lr, x = xp * 2;
    const double* wbase = w2d + co0 * 288;
    float bb0 = b2[co0], bb1 = b2[co0 + 1];
    float w2s[4] = {0.f, 0.f, 0.f, 0.f};
    float y3a[4] = {0.f, 0.f, 0.f, 0.f};
    float y3b[4] = {0.f, 0.f, 0.f, 0.f};
    for (int t = 0; t < 25; ++t) {
        const float* a2o = a2ch + (size_t)t * 921600;
        double acc0[2] = {0.0, 0.0}, acc1[2] = {0.0, 0.0};
        #pragma unroll 2
        for (int ci = 0; ci < 32; ++ci) {
            const float* r = a2o + ((b * 32 + ci) * 30 + y) * 30 + x;
            const double* wp = wbase + ci * 9;   // wave-uniform -> SGPR loads
            #pragma unroll
            for (int ky = 0; ky < 3; ++ky) {
                float2 lo = *(const float2*)(r + ky * 30);
                float2 hi = *(const float2*)(r + ky * 30 + 2);
                double v0 = (double)lo.x, v1 = (double)lo.y;
                double v2 = (double)hi.x, v3 = (double)hi.y;
                #pragma unroll
                for (int j = 0; j < 2; ++j) {
                    const double* wj = wp + j * 288 + ky * 3;
                    acc0[j] += v0*wj[0] + v1*wj[1] + v2*wj[2];
                    acc1[j] += v1*wj[0] + v2*wj[1] + v3*wj[2];
                }
            }
        }
        float* a3o = a3ch + (size_t)t * 802816;
        #pragma unroll
        for (int j = 0; j < 2; ++j) {
            float bb = j ? bb1 : bb0;
            #pragma unroll
            for (int u = 0; u < 2; ++u) {
                int s = j * 2 + u;
                int idx = (b * 32 + co0 + j) * 784 + y * 28 + x + u;
                float cur = __fadd_rn((float)(u ? acc1[j] : acc0[j]), bb);
                float vn = __fadd_rn(__fmul_rn(eta_m, w2s[s]), cur);
                float sn = vn > 1.0f ? 1.0f : 0.0f;
                w2s[s] = vn > 1.0f ? 0.0f : vn;
                float yv = axon_step(A1, A2, y3a[s], y3b[s], sn);
                y3b[s] = y3a[s]; y3a[s] = yv;
                a3o[idx] = yv;
            }
        }
    }
}

// ---- conv3g: all-t conv3+b3+LIF3+axon4+pool+axon5 -> a5ch[25] ; reg states ----
// grid: b(32) x coq(16) x sp(2) = 1024 blocks, 256 thr
__global__ __launch_bounds__(256) void conv3g_kernel(
        const float* __restrict__ a3ch, const double* __restrict__ w3d,
        const float* __restrict__ b3, float* __restrict__ a5ch,
        float A1, float A2, float eta_m) {
    int bid = blockIdx.x;
    int b = bid & 31, coq = (bid >> 5) & 15, sp = bid >> 9;
    int co0 = coq * 4;
    int row0 = sp ? 14 : 0;
    int nrow = sp ? 12 : 14;
    int pr0  = sp ? 7 : 0;
    int npr  = sp ? 6 : 7;
    int tid = threadIdx.x;
    __shared__ float tile[4 * 364];   // [4co][<=14 rows][26]
    int npair = nrow * 13;
    int npool = npr * 13 * 4;
    const double* wbase = w3d + co0 * 288;
    // conv-role geometry
    int lr = 0, xp = 0, y = 0, x = 0;
    bool convAct = tid < npair;
    if (convAct) { lr = tid / 13; xp = tid % 13; y = row0 + lr; x = xp * 2; }
    float bb[4];
    #pragma unroll
    for (int j = 0; j < 4; ++j) bb[j] = b3[co0 + j];
    float w3s[8], y4a[8], y4b[8];
    #pragma unroll
    for (int s = 0; s < 8; ++s) { w3s[s] = 0.f; y4a[s] = 0.f; y4b[s] = 0.f; }
    // pool-role geometry (2 static slots)
    float y5a[2] = {0.f, 0.f}, y5b[2] = {0.f, 0.f};
    for (int t = 0; t < 25; ++t) {
        if (convAct) {
            const float* a3o = a3ch + (size_t)t * 802816;
            double acc0[4] = {0.0, 0.0, 0.0, 0.0};
            double acc1[4] = {0.0, 0.0, 0.0, 0.0};
            #pragma unroll 2
            for (int ci = 0; ci < 32; ++ci) {
                const float* r = a3o + ((b * 32 + ci) * 28 + y) * 28 + x;
                const double* wp = wbase + ci * 9;   // SGPR loads
                #pragma unroll
                for (int ky = 0; ky < 3; ++ky) {
                    float2 lo = *(const float2*)(r + ky * 28);
                    float2 hi = *(const float2*)(r + ky * 28 + 2);
                    double v0 = (double)lo.x, v1 = (double)lo.y;
                    double v2 = (double)hi.x, v3 = (double)hi.y;
                    #pragma unroll
                    for (int j = 0; j < 4; ++j) {
                        const double* wj = wp + j * 288 + ky * 3;
                        acc0[j] += v0*wj[0] + v1*wj[1] + v2*wj[2];
                        acc1[j] += v1*wj[0] + v2*wj[1] + v3*wj[2];
                    }
                }
            }
            #pragma unroll
            for (int j = 0; j < 4; ++j) {
                #pragma unroll
                for (int u = 0; u < 2; ++u) {
                    int s = j * 2 + u;
                    float cur = __fadd_rn((float)(u ? acc1[j] : acc0[j]), bb[j]);
                    float vn = __fadd_rn(__fmul_rn(eta_m, w3s[s]), cur);
                    float sn = vn > 1.0f ? 1.0f : 0.0f;
                    w3s[s] = vn > 1.0f ? 0.0f : vn;
                    float a4 = axon_step(A1, A2, y4a[s], y4b[s], sn);
                    y4b[s] = y4a[s]; y4a[s] = a4;
                    tile[j * 364 + lr * 26 + x + u] = a4;
                }
            }
        }
        __syncthreads();
        float* a5o = a5ch + (size_t)t * 346112;
        #pragma unroll
        for (int s = 0; s < 2; ++s) {
            int q = tid + s * 256;
            if (q < npool) {
                int j = q / (npr * 13), pp = q % (npr * 13);
                int pry = pp / 13, px = pp % 13;
                int pr = pr0 + pry;
                int tlr = 2 * pr - row0;
                const float* tp = tile + j * 364 + tlr * 26 + 2 * px;
                float m = fmaxf(fmaxf(tp[0], tp[1]), fmaxf(tp[26], tp[27]));
                int idx = (b * 64 + co0 + j) * 169 + pr * 13 + px;
                float yv = axon_step(A1, A2, y5a[s], y5b[s], m);
                y5b[s] = y5a[s]; y5a[s] = yv;
                a5o[idx] = yv;
            }
        }
        __syncthreads();
    }
}

// ---- conv5g: all-t conv5+b5+LIF5+axon6+pool+flatten+axon7 -> a7ch[25] ----
// grid: b(32) x co(64) = 2048 blocks, 128 threads; 9 acc chains; reg states
__global__ __launch_bounds__(128) void conv5g_kernel(
        const float* __restrict__ a5ch, const double* __restrict__ w5d,
        const float* __restrict__ b5, float* __restrict__ a7ch,
        float A1, float A2, float eta_m) {
    int bid = blockIdx.x;
    int b = bid & 31, co = bid >> 5;
    int tid = threadIdx.x;
    __shared__ float tile[121];
    const double* wbase = w5d + co * 576;
    float bb = b5[co];
    float w5s = 0.f, y6a = 0.f, y6b = 0.f;
    float y7a = 0.f, y7b = 0.f;
    int yy = tid / 11, xx = tid % 11;
    int py = tid / 5, px = tid % 5;
    for (int t = 0; t < 25; ++t) {
        if (tid < 121) {
            const float* a5o = a5ch + (size_t)t * 346112;
            double a[9] = {0,0,0,0,0,0,0,0,0};
            #pragma unroll 2
            for (int ci = 0; ci < 64; ++ci) {
                const float* r = a5o + (b * 64 + ci) * 169 + yy * 13 + xx;
                const double* wp = wbase + ci * 9;   // SGPR loads
                a[0] += (double)r[0]  * wp[0];
                a[1] += (double)r[1]  * wp[1];
                a[2] += (double)r[2]  * wp[2];
                a[3] += (double)r[13] * wp[3];
                a[4] += (double)r[14] * wp[4];
                a[5] += (double)r[15] * wp[5];
                a[6] += (double)r[26] * wp[6];
                a[7] += (double)r[27] * wp[7];
                a[8] += (double)r[28] * wp[8];
            }
            double acc = ((a[0]+a[1])+(a[2]+a[3])) + ((a[4]+a[5])+(a[6]+a[7])) + a[8];
            float cur = __fadd_rn((float)acc, bb);
            float vn = __fadd_rn(__fmul_rn(eta_m, w5s), cur);
            float sn = vn > 1.0f ? 1.0f : 0.0f;
            w5s = vn > 1.0f ? 0.0f : vn;
            float a6 = axon_step(A1, A2, y6a, y6b, sn);
            y6b = y6a; y6a = a6;
            tile[tid] = a6;
        }
        __syncthreads();
        if (tid < 25) {
            const float* tp = tile + (2*py)*11 + 2*px;
            float m = fmaxf(fmaxf(tp[0], tp[1]), fmaxf(tp[11], tp[12]));
            float yv = axon_step(A1, A2, y7a, y7b, m);
            y7b = y7a; y7a = yv;
            a7ch[(size_t)t * 51200 + b * 1600 + co * 25 + tid] = yv;
        }
        __syncthreads();
    }
}

// ---- fc7g: all-t fc7+b7+LIF7+axon8 -> a8ch[25] ; 1024 blocks ----
__global__ __launch_bounds__(256) void fc7g_kernel(
        const float* __restrict__ a7ch, const float* __restrict__ w7,
        const float* __restrict__ b7, float* __restrict__ a8ch,
        float A1, float A2, float eta_m) {
    int bid = blockIdx.x;
    int b = bid & 31, ot = bid >> 5;   // 32 tiles of 16 outputs
    int tid = threadIdx.x;
    int wave = tid >> 6, lane = tid & 63;
    __shared__ float sIn[1600];
    float w7s[4] = {0.f, 0.f, 0.f, 0.f};
    float y8a[4] = {0.f, 0.f, 0.f, 0.f};
    float y8b[4] = {0.f, 0.f, 0.f, 0.f};
    for (int t = 0; t < 25; ++t) {
        const float* a7o = a7ch + (size_t)t * 51200 + b * 1600;
        for (int i = tid; i < 1600; i += 256) sIn[i] = a7o[i];
        __syncthreads();
        float* a8o = a8ch + (size_t)t * 16384;
        #pragma unroll
        for (int oi = 0; oi < 4; ++oi) {
            int o = ot * 16 + wave * 4 + oi;
            const float* wr = w7 + o * 1600;
            double acc = 0.0;
            #pragma unroll
            for (int i = 0; i < 25; ++i)
                acc += (double)sIn[i * 64 + lane] * (double)wr[i * 64 + lane];
            #pragma unroll
            for (int off = 32; off > 0; off >>= 1)
                acc += __shfl_down(acc, off);
            if (lane == 0) {
                float cur = __fadd_rn((float)acc, b7[o]);
                float vn = __fadd_rn(__fmul_rn(eta_m, w7s[oi]), cur);
                float sn = vn > 1.0f ? 1.0f : 0.0f;
                w7s[oi] = vn > 1.0f ? 0.0f : vn;
                float yv = axon_step(A1, A2, y8a[oi], y8b[oi], sn);
                y8b[oi] = y8a[oi]; y8a[oi] = yv;
                a8o[b * 512 + o] = yv;
            }
        }
        __syncthreads();
    }
}

// ---- fc8g: all-t fc8+b8+LIF8 -> out [B,10,T] ; 32 blocks ----
__global__ __launch_bounds__(64) void fc8g_kernel(
        const float* __restrict__ a8ch, const float* __restrict__ w8,
        const float* __restrict__ b8, float* __restrict__ out, float eta_m) {
    int b = blockIdx.x;
    int lane = threadIdx.x;
    float w8s[10];
    #pragma unroll
    for (int o = 0; o < 10; ++o) w8s[o] = 0.f;
    for (int t = 0; t < 25; ++t) {
        const float* sr = a8ch + (size_t)t * 16384 + b * 512;
        #pragma unroll
        for (int o = 0; o < 10; ++o) {
            const float* wr = w8 + o * 512;
            double acc = 0.0;
            #pragma unroll
            for (int i = 0; i < 8; ++i)
                acc += (double)sr[i*64+lane] * (double)wr[i*64+lane];
            #pragma unroll
            for (int off = 32; off > 0; off >>= 1)
                acc += __shfl_down(acc, off);
            if (lane == 0) {
                float cur = __fadd_rn((float)acc, b8[o]);
                float vn = __fadd_rn(__fmul_rn(eta_m, w8s[o]), cur);
                float sn = vn > 1.0f ? 1.0f : 0.0f;
                w8s[o] = vn > 1.0f ? 0.0f : vn;
                out[(b * 10 + o) * 25 + t] = sn;
            }
        }
    }
}

extern "C" void kernel_launch(void* const* d_in, const int* in_sizes, int n_in,
                              void* d_out, int out_size, void* d_ws, size_t ws_size,
                              hipStream_t stream) {
    (void)in_sizes; (void)n_in;
    const float* inp = (const float*)d_in[0];
    const float* a1w = (const float*)d_in[1];
    const float* a1b = (const float*)d_in[2];
    const float* w2  = (const float*)d_in[3];
    const float* b2  = (const float*)d_in[4];
    const float* w3  = (const float*)d_in[5];
    const float* b3  = (const float*)d_in[6];
    const float* w5  = (const float*)d_in[7];
    const float* b5  = (const float*)d_in[8];
    const float* w7  = (const float*)d_in[9];
    const float* b7  = (const float*)d_in[10];
    const float* w8  = (const float*)d_in[11];
    const float* b8  = (const float*)d_in[12];
    float* out = (float*)d_out;
    float* ws  = (float*)d_ws;

    const float em = (float)exp(-0.25);
    const float es = (float)exp(-1.0);
    const float A1 = em + es;
    const float A2 = -(em * es);

    // layout (float units); f64 arrays first for 8B alignment
    size_t off = 0;
    auto nf = [&](size_t n) { size_t o = off; off += n; return o; };
    size_t o_w2d   = nf(2*9216);
    size_t o_w3d   = nf(2*18432);
    size_t o_w5d   = nf(2*36864);
    size_t o_frame = nf(921600);
    size_t o_a2ch  = nf((size_t)25 * 921600);
    size_t o_a3ch  = nf((size_t)25 * 802816);
    size_t o_a5ch  = nf((size_t)25 * 346112);
    size_t o_a7ch  = nf((size_t)25 * 51200);
    size_t o_a8ch  = nf((size_t)25 * 16384);

    if (ws_size < off * sizeof(float)) {
        diag_kernel<<<(out_size + 255) / 256, 256, 0, stream>>>(
            out, 100.0f + (float)(ws_size >> 20), out_size);
        return;
    }

    wcvt_kernel<<<144, 256, 0, stream>>>(w2, w3, w5,
                                         (double*)(ws + o_w2d),
                                         (double*)(ws + o_w3d),
                                         (double*)(ws + o_w5d));
    ann1_kernel<<<1024, 256, 0, stream>>>(inp, a1w, a1b, ws + o_frame);
    axon2g_kernel<<<1800, 256, 0, stream>>>((const float2*)(ws + o_frame),
                                            ws + o_a2ch, A1, A2);
    conv2g_kernel<<<1024, 256, 0, stream>>>(ws + o_a2ch,
                                            (const double*)(ws + o_w2d), b2,
                                            ws + o_a3ch, A1, A2, em);
    conv3g_kernel<<<1024, 256, 0, stream>>>(ws + o_a3ch,
                                            (const double*)(ws + o_w3d), b3,
                                            ws + o_a5ch, A1, A2, em);
    conv5g_kernel<<<2048, 128, 0, stream>>>(ws + o_a5ch,
                                            (const double*)(ws + o_w5d), b5,
                                            ws + o_a7ch, A1, A2, em);
    fc7g_kernel<<<1024, 256, 0, stream>>>(ws + o_a7ch, w7, b7,
                                          ws + o_a8ch, A1, A2, em);
    fc8g_kernel<<<32, 64, 0, stream>>>(ws + o_a8ch, w8, b8, out, em);

    canary_kernel<<<1, 256, 0, stream>>>(out, out_size);
}

// Round 16
// 2069.893 us; speedup vs baseline: 1.1324x; 1.1324x over previous
//
#include <hip/hip_runtime.h>
#include <math.h>

// Center-tracking f32 SNN: reductions in f64 (rounded once to f32 at the
// reference's materialization points), elementwise chains in exact-order f32
// round-to-nearest ops (no FMA), constants as f32 values.
// R16: R15 layer-per-kernel + t-PAIR unrolling inside conv2g/conv3g/conv5g
// (conv reductions for t,t+1 interleaved for 2x memory-level parallelism;
// state updates stay in exact t order -- bit-exact).

__device__ __forceinline__ float axon_step(float A1, float A2, float y1, float y2, float x) {
    return __fadd_rn(__fadd_rn(__fmul_rn(A1, y1), __fmul_rn(A2, y2)), x);
}

__global__ void diag_kernel(float* out, float v, int n) {
    int i = blockIdx.x * 256 + threadIdx.x;
    if (i < n) out[i] = v;
}

__global__ void canary_kernel(float* out, int n) {
    __shared__ float ssum[256];
    float s = 0.f;
    for (int i = threadIdx.x; i < n; i += 256) s += out[i];
    ssum[threadIdx.x] = s;
    __syncthreads();
    for (int k = 128; k > 0; k >>= 1) {
        if (threadIdx.x < k) ssum[threadIdx.x] += ssum[threadIdx.x + k];
        __syncthreads();
    }
    if (threadIdx.x == 0 && ssum[0] == 0.0f) out[0] = 444.0f;
}

// ---- one-time: weights f32 -> f64 (exact) ----
__global__ __launch_bounds__(256) void wcvt_kernel(
        const float* __restrict__ w2, const float* __restrict__ w3,
        const float* __restrict__ w5,
        double* __restrict__ w2d, double* __restrict__ w3d,
        double* __restrict__ w5d) {
    int i = blockIdx.x * 256 + threadIdx.x;
    if (i < 9216)  w2d[i] = (double)w2[i];
    if (i < 18432) w3d[i] = (double)w3[i];
    if (i < 36864) w5d[i] = (double)w5[i];
}

// ---- ann1: frame = sigmoid(conv+b), once ----
__global__ __launch_bounds__(256) void ann1_kernel(
        const float* __restrict__ in, const float* __restrict__ w,
        const float* __restrict__ bias, float* __restrict__ frame) {
    int bid = blockIdx.x;
    int b = bid & 31, co = bid >> 5;
    int tid = threadIdx.x;
    __shared__ double wsh[27];
    if (tid < 27) wsh[tid] = (double)w[co * 27 + tid];
    __syncthreads();
    float bb = bias[co];
    for (int p = tid; p < 900; p += 256) {
        int y = p / 30, x = p % 30;
        double acc = 0.0;
        #pragma unroll
        for (int ci = 0; ci < 3; ++ci) {
            const float* r = in + ((b * 3 + ci) * 32 + y) * 32 + x;
            const double* wp = wsh + ci * 9;
            #pragma unroll
            for (int ky = 0; ky < 3; ++ky)
                acc += (double)r[ky*32+0]*wp[ky*3+0] + (double)r[ky*32+1]*wp[ky*3+1]
                     + (double)r[ky*32+2]*wp[ky*3+2];
        }
        float z = __fadd_rn((float)acc, bb);
        frame[((b * 32 + co) * 30 + y) * 30 + x] =
            (float)(1.0 / (1.0 + exp(-(double)z)));
    }
}

// ---- axon2g: 25-step exact-order f32 IIR in registers -> a2ch[25] ----
__global__ __launch_bounds__(256) void axon2g_kernel(
        const float2* __restrict__ frame2, float* __restrict__ a2ch,
        float A1, float A2) {
    int g = blockIdx.x * 256 + threadIdx.x;  // 460800 exact
    float2 f = frame2[g];
    float y1a = 0.f, y2a = 0.f, y1b = 0.f, y2b = 0.f;
    #pragma unroll
    for (int k = 0; k < 25; ++k) {
        float v0 = axon_step(A1, A2, y1a, y2a, f.x);
        float v1 = axon_step(A1, A2, y1b, y2b, f.y);
        ((float2*)(a2ch + (size_t)k * 921600))[g] = make_float2(v0, v1);
        y2a = y1a; y1a = v0;
        y2b = y1b; y1b = v1;
    }
}

// ---- conv2g: all-t conv2+b2+LIF2+axon3 -> a3ch[25] ; t-pair unrolled ----
// grid: b(32) x cop(16) x sp(2) = 1024 blocks, 256 thr (196 active); no LDS
__global__ __launch_bounds__(256) void conv2g_kernel(
        const float* __restrict__ a2ch, const double* __restrict__ w2d,
        const float* __restrict__ b2, float* __restrict__ a3ch,
        float A1, float A2, float eta_m) {
    int bid = blockIdx.x;
    int b = bid & 31, cop = (bid >> 5) & 15, sp = (bid >> 9) & 1;
    int co0 = cop * 2;
    int row0 = sp * 14;
    int p = threadIdx.x;
    if (p >= 196) return;
    int lr = p / 14, xp = p % 14;
    int y = row0 + lr, x = xp * 2;
    const double* wbase = w2d + co0 * 288;
    float bb0 = b2[co0], bb1 = b2[co0 + 1];
    float w2s[4] = {0.f, 0.f, 0.f, 0.f};
    float y3a[4] = {0.f, 0.f, 0.f, 0.f};
    float y3b[4] = {0.f, 0.f, 0.f, 0.f};
    size_t roffb = ((size_t)(b * 32) * 30 + y) * 30 + x;
    for (int tt = 0; tt < 12; ++tt) {
        const float* p0 = a2ch + (size_t)(2 * tt) * 921600;
        const float* p1 = p0 + 921600;
        double e00[2] = {0.0, 0.0}, e01[2] = {0.0, 0.0};   // t0: x, x+1
        double e10[2] = {0.0, 0.0}, e11[2] = {0.0, 0.0};   // t1: x, x+1
        #pragma unroll 2
        for (int ci = 0; ci < 32; ++ci) {
            const float* r0 = p0 + roffb + ci * 900;
            const float* r1 = p1 + roffb + ci * 900;
            const double* wp = wbase + ci * 9;
            #pragma unroll
            for (int ky = 0; ky < 3; ++ky) {
                float2 lo0 = *(const float2*)(r0 + ky * 30);
                float2 hi0 = *(const float2*)(r0 + ky * 30 + 2);
                float2 lo1 = *(const float2*)(r1 + ky * 30);
                float2 hi1 = *(const float2*)(r1 + ky * 30 + 2);
                double u0 = (double)lo0.x, u1 = (double)lo0.y;
                double u2 = (double)hi0.x, u3 = (double)hi0.y;
                double v0 = (double)lo1.x, v1 = (double)lo1.y;
                double v2 = (double)hi1.x, v3 = (double)hi1.y;
                #pragma unroll
                for (int j = 0; j < 2; ++j) {
                    const double* wj = wp + j * 288 + ky * 3;
                    e00[j] += u0*wj[0] + u1*wj[1] + u2*wj[2];
                    e01[j] += u1*wj[0] + u2*wj[1] + u3*wj[2];
                    e10[j] += v0*wj[0] + v1*wj[1] + v2*wj[2];
                    e11[j] += v1*wj[0] + v2*wj[1] + v3*wj[2];
                }
            }
        }
        float* a3o0 = a3ch + (size_t)(2 * tt) * 802816;
        float* a3o1 = a3o0 + 802816;
        #pragma unroll
        for (int j = 0; j < 2; ++j) {
            float bb = j ? bb1 : bb0;
            #pragma unroll
            for (int u = 0; u < 2; ++u) {
                int s = j * 2 + u;
                int idx = (b * 32 + co0 + j) * 784 + y * 28 + x + u;
                // t0
                float cur = __fadd_rn((float)(u ? e01[j] : e00[j]), bb);
                float vn = __fadd_rn(__fmul_rn(eta_m, w2s[s]), cur);
                float sn = vn > 1.0f ? 1.0f : 0.0f;
                w2s[s] = vn > 1.0f ? 0.0f : vn;
                float yv = axon_step(A1, A2, y3a[s], y3b[s], sn);
                y3b[s] = y3a[s]; y3a[s] = yv;
                a3o0[idx] = yv;
                // t1
                cur = __fadd_rn((float)(u ? e11[j] : e10[j]), bb);
                vn = __fadd_rn(__fmul_rn(eta_m, w2s[s]), cur);
                sn = vn > 1.0f ? 1.0f : 0.0f;
                w2s[s] = vn > 1.0f ? 0.0f : vn;
                yv = axon_step(A1, A2, y3a[s], y3b[s], sn);
                y3b[s] = y3a[s]; y3a[s] = yv;
                a3o1[idx] = yv;
            }
        }
    }
    {   // tail t = 24
        const float* a2o = a2ch + (size_t)24 * 921600;
        double e00[2] = {0.0, 0.0}, e01[2] = {0.0, 0.0};
        #pragma unroll 2
        for (int ci = 0; ci < 32; ++ci) {
            const float* r = a2o + roffb + ci * 900;
            const double* wp = wbase + ci * 9;
            #pragma unroll
            for (int ky = 0; ky < 3; ++ky) {
                float2 lo = *(const float2*)(r + ky * 30);
                float2 hi = *(const float2*)(r + ky * 30 + 2);
                double u0 = (double)lo.x, u1 = (double)lo.y;
                double u2 = (double)hi.x, u3 = (double)hi.y;
                #pragma unroll
                for (int j = 0; j < 2; ++j) {
                    const double* wj = wp + j * 288 + ky * 3;
                    e00[j] += u0*wj[0] + u1*wj[1] + u2*wj[2];
                    e01[j] += u1*wj[0] + u2*wj[1] + u3*wj[2];
                }
            }
        }
        float* a3o = a3ch + (size_t)24 * 802816;
        #pragma unroll
        for (int j = 0; j < 2; ++j) {
            float bb = j ? bb1 : bb0;
            #pragma unroll
            for (int u = 0; u < 2; ++u) {
                int s = j * 2 + u;
                int idx = (b * 32 + co0 + j) * 784 + y * 28 + x + u;
                float cur = __fadd_rn((float)(u ? e01[j] : e00[j]), bb);
                float vn = __fadd_rn(__fmul_rn(eta_m, w2s[s]), cur);
                float sn = vn > 1.0f ? 1.0f : 0.0f;
                w2s[s] = vn > 1.0f ? 0.0f : vn;
                float yv = axon_step(A1, A2, y3a[s], y3b[s], sn);
                y3b[s] = y3a[s]; y3a[s] = yv;
                a3o[idx] = yv;
            }
        }
    }
}

// ---- conv3g: all-t conv3+b3+LIF3+axon4+pool+axon5 -> a5ch[25] ; t-pair ----
// grid: b(32) x coq(16) x sp(2) = 1024 blocks, 256 thr
__global__ __launch_bounds__(256) void conv3g_kernel(
        const float* __restrict__ a3ch, const double* __restrict__ w3d,
        const float* __restrict__ b3, float* __restrict__ a5ch,
        float A1, float A2, float eta_m) {
    int bid = blockIdx.x;
    int b = bid & 31, coq = (bid >> 5) & 15, sp = bid >> 9;
    int co0 = coq * 4;
    int row0 = sp ? 14 : 0;
    int nrow = sp ? 12 : 14;
    int pr0  = sp ? 7 : 0;
    int npr  = sp ? 6 : 7;
    int tid = threadIdx.x;
    __shared__ float tile0[4 * 364];
    __shared__ float tile1[4 * 364];
    int npair = nrow * 13;
    int npool = npr * 13 * 4;
    const double* wbase = w3d + co0 * 288;
    int lr = 0, xp = 0, y = 0, x = 0;
    bool convAct = tid < npair;
    if (convAct) { lr = tid / 13; xp = tid % 13; y = row0 + lr; x = xp * 2; }
    float bb[4];
    #pragma unroll
    for (int j = 0; j < 4; ++j) bb[j] = b3[co0 + j];
    float w3s[8], y4a[8], y4b[8];
    #pragma unroll
    for (int s = 0; s < 8; ++s) { w3s[s] = 0.f; y4a[s] = 0.f; y4b[s] = 0.f; }
    float y5a[2] = {0.f, 0.f}, y5b[2] = {0.f, 0.f};
    size_t roffb = ((size_t)(b * 32) * 28 + y) * 28 + x;
    for (int tt = 0; tt < 12; ++tt) {
        if (convAct) {
            const float* p0 = a3ch + (size_t)(2 * tt) * 802816;
            const float* p1 = p0 + 802816;
            double e00[4] = {0,0,0,0}, e01[4] = {0,0,0,0};
            double e10[4] = {0,0,0,0}, e11[4] = {0,0,0,0};
            #pragma unroll 2
            for (int ci = 0; ci < 32; ++ci) {
                const float* r0 = p0 + roffb + ci * 784;
                const float* r1 = p1 + roffb + ci * 784;
                const double* wp = wbase + ci * 9;
                #pragma unroll
                for (int ky = 0; ky < 3; ++ky) {
                    float2 lo0 = *(const float2*)(r0 + ky * 28);
                    float2 hi0 = *(const float2*)(r0 + ky * 28 + 2);
                    float2 lo1 = *(const float2*)(r1 + ky * 28);
                    float2 hi1 = *(const float2*)(r1 + ky * 28 + 2);
                    double u0 = (double)lo0.x, u1 = (double)lo0.y;
                    double u2 = (double)hi0.x, u3 = (double)hi0.y;
                    double v0 = (double)lo1.x, v1 = (double)lo1.y;
                    double v2 = (double)hi1.x, v3 = (double)hi1.y;
                    #pragma unroll
                    for (int j = 0; j < 4; ++j) {
                        const double* wj = wp + j * 288 + ky * 3;
                        e00[j] += u0*wj[0] + u1*wj[1] + u2*wj[2];
                        e01[j] += u1*wj[0] + u2*wj[1] + u3*wj[2];
                        e10[j] += v0*wj[0] + v1*wj[1] + v2*wj[2];
                        e11[j] += v1*wj[0] + v2*wj[1] + v3*wj[2];
                    }
                }
            }
            #pragma unroll
            for (int j = 0; j < 4; ++j) {
                #pragma unroll
                for (int u = 0; u < 2; ++u) {
                    int s = j * 2 + u;
                    // t0
                    float cur = __fadd_rn((float)(u ? e01[j] : e00[j]), bb[j]);
                    float vn = __fadd_rn(__fmul_rn(eta_m, w3s[s]), cur);
                    float sn = vn > 1.0f ? 1.0f : 0.0f;
                    w3s[s] = vn > 1.0f ? 0.0f : vn;
                    float a4 = axon_step(A1, A2, y4a[s], y4b[s], sn);
                    y4b[s] = y4a[s]; y4a[s] = a4;
                    tile0[j * 364 + lr * 26 + x + u] = a4;
                    // t1
                    cur = __fadd_rn((float)(u ? e11[j] : e10[j]), bb[j]);
                    vn = __fadd_rn(__fmul_rn(eta_m, w3s[s]), cur);
                    sn = vn > 1.0f ? 1.0f : 0.0f;
                    w3s[s] = vn > 1.0f ? 0.0f : vn;
                    a4 = axon_step(A1, A2, y4a[s], y4b[s], sn);
                    y4b[s] = y4a[s]; y4a[s] = a4;
                    tile1[j * 364 + lr * 26 + x + u] = a4;
                }
            }
        }
        __syncthreads();
        float* a5o0 = a5ch + (size_t)(2 * tt) * 346112;
        float* a5o1 = a5o0 + 346112;
        #pragma unroll
        for (int s = 0; s < 2; ++s) {
            int q = tid + s * 256;
            if (q < npool) {
                int j = q / (npr * 13), pp = q % (npr * 13);
                int pry = pp / 13, px = pp % 13;
                int pr = pr0 + pry;
                int tlr = 2 * pr - row0;
                int toff = j * 364 + tlr * 26 + 2 * px;
                int idx = (b * 64 + co0 + j) * 169 + pr * 13 + px;
                // t0
                const float* tp = tile0 + toff;
                float m = fmaxf(fmaxf(tp[0], tp[1]), fmaxf(tp[26], tp[27]));
                float yv = axon_step(A1, A2, y5a[s], y5b[s], m);
                y5b[s] = y5a[s]; y5a[s] = yv;
                a5o0[idx] = yv;
                // t1
                tp = tile1 + toff;
                m = fmaxf(fmaxf(tp[0], tp[1]), fmaxf(tp[26], tp[27]));
                yv = axon_step(A1, A2, y5a[s], y5b[s], m);
                y5b[s] = y5a[s]; y5a[s] = yv;
                a5o1[idx] = yv;
            }
        }
        __syncthreads();
    }
    {   // tail t = 24
        if (convAct) {
            const float* a3o = a3ch + (size_t)24 * 802816;
            double e00[4] = {0,0,0,0}, e01[4] = {0,0,0,0};
            #pragma unroll 2
            for (int ci = 0; ci < 32; ++ci) {
                const float* r = a3o + roffb + ci * 784;
                const double* wp = wbase + ci * 9;
                #pragma unroll
                for (int ky = 0; ky < 3; ++ky) {
                    float2 lo = *(const float2*)(r + ky * 28);
                    float2 hi = *(const float2*)(r + ky * 28 + 2);
                    double u0 = (double)lo.x, u1 = (double)lo.y;
                    double u2 = (double)hi.x, u3 = (double)hi.y;
                    #pragma unroll
                    for (int j = 0; j < 4; ++j) {
                        const double* wj = wp + j * 288 + ky * 3;
                        e00[j] += u0*wj[0] + u1*wj[1] + u2*wj[2];
                        e01[j] += u1*wj[0] + u2*wj[1] + u3*wj[2];
                    }
                }
            }
            #pragma unroll
            for (int j = 0; j < 4; ++j) {
                #pragma unroll
                for (int u = 0; u < 2; ++u) {
                    int s = j * 2 + u;
                    float cur = __fadd_rn((float)(u ? e01[j] : e00[j]), bb[j]);
                    float vn = __fadd_rn(__fmul_rn(eta_m, w3s[s]), cur);
                    float sn = vn > 1.0f ? 1.0f : 0.0f;
                    w3s[s] = vn > 1.0f ? 0.0f : vn;
                    float a4 = axon_step(A1, A2, y4a[s], y4b[s], sn);
                    y4b[s] = y4a[s]; y4a[s] = a4;
                    tile0[j * 364 + lr * 26 + x + u] = a4;
                }
            }
        }
        __syncthreads();
        float* a5o = a5ch + (size_t)24 * 346112;
        #pragma unroll
        for (int s = 0; s < 2; ++s) {
            int q = tid + s * 256;
            if (q < npool) {
                int j = q / (npr * 13), pp = q % (npr * 13);
                int pry = pp / 13, px = pp % 13;
                int pr = pr0 + pry;
                int tlr = 2 * pr - row0;
                const float* tp = tile0 + j * 364 + tlr * 26 + 2 * px;
                float m = fmaxf(fmaxf(tp[0], tp[1]), fmaxf(tp[26], tp[27]));
                int idx = (b * 64 + co0 + j) * 169 + pr * 13 + px;
                float yv = axon_step(A1, A2, y5a[s], y5b[s], m);
                y5b[s] = y5a[s]; y5a[s] = yv;
                a5o[idx] = yv;
            }
        }
    }
}

// ---- conv5g: all-t conv5+b5+LIF5+axon6+pool+flatten+axon7 -> a7ch[25] ----
// grid: b(32) x co(64) = 2048 blocks, 128 threads; t-pair, 18 f64 chains
__global__ __launch_bounds__(128) void conv5g_kernel(
        const float* __restrict__ a5ch, const double* __restrict__ w5d,
        const float* __restrict__ b5, float* __restrict__ a7ch,
        float A1, float A2, float eta_m) {
    int bid = blockIdx.x;
    int b = bid & 31, co = bid >> 5;
    int tid = threadIdx.x;
    __shared__ float tile0[121];
    __shared__ float tile1[121];
    const double* wbase = w5d + co * 576;
    float bb = b5[co];
    float w5s = 0.f, y6a = 0.f, y6b = 0.f;
    float y7a = 0.f, y7b = 0.f;
    int yy = tid / 11, xx = tid % 11;
    int py = tid / 5, px = tid % 5;
    size_t roffb = (size_t)(b * 64) * 169 + yy * 13 + xx;
    for (int tt = 0; tt < 12; ++tt) {
        if (tid < 121) {
            const float* p0 = a5ch + (size_t)(2 * tt) * 346112;
            const float* p1 = p0 + 346112;
            double a0[9] = {0,0,0,0,0,0,0,0,0};
            double a1[9] = {0,0,0,0,0,0,0,0,0};
            #pragma unroll 2
            for (int ci = 0; ci < 64; ++ci) {
                const float* r0 = p0 + roffb + ci * 169;
                const float* r1 = p1 + roffb + ci * 169;
                const double* wp = wbase + ci * 9;
                a0[0] += (double)r0[0]  * wp[0];
                a0[1] += (double)r0[1]  * wp[1];
                a0[2] += (double)r0[2]  * wp[2];
                a0[3] += (double)r0[13] * wp[3];
                a0[4] += (double)r0[14] * wp[4];
                a0[5] += (double)r0[15] * wp[5];
                a0[6] += (double)r0[26] * wp[6];
                a0[7] += (double)r0[27] * wp[7];
                a0[8] += (double)r0[28] * wp[8];
                a1[0] += (double)r1[0]  * wp[0];
                a1[1] += (double)r1[1]  * wp[1];
                a1[2] += (double)r1[2]  * wp[2];
                a1[3] += (double)r1[13] * wp[3];
                a1[4] += (double)r1[14] * wp[4];
                a1[5] += (double)r1[15] * wp[5];
                a1[6] += (double)r1[26] * wp[6];
                a1[7] += (double)r1[27] * wp[7];
                a1[8] += (double)r1[28] * wp[8];
            }
            double acc0 = ((a0[0]+a0[1])+(a0[2]+a0[3])) + ((a0[4]+a0[5])+(a0[6]+a0[7])) + a0[8];
            double acc1 = ((a1[0]+a1[1])+(a1[2]+a1[3])) + ((a1[4]+a1[5])+(a1[6]+a1[7])) + a1[8];
            // t0
            float cur = __fadd_rn((float)acc0, bb);
            float vn = __fadd_rn(__fmul_rn(eta_m, w5s), cur);
            float sn = vn > 1.0f ? 1.0f : 0.0f;
            w5s = vn > 1.0f ? 0.0f : vn;
            float a6 = axon_step(A1, A2, y6a, y6b, sn);
            y6b = y6a; y6a = a6;
            tile0[tid] = a6;
            // t1
            cur = __fadd_rn((float)acc1, bb);
            vn = __fadd_rn(__fmul_rn(eta_m, w5s), cur);
            sn = vn > 1.0f ? 1.0f : 0.0f;
            w5s = vn > 1.0f ? 0.0f : vn;
            a6 = axon_step(A1, A2, y6a, y6b, sn);
            y6b = y6a; y6a = a6;
            tile1[tid] = a6;
        }
        __syncthreads();
        if (tid < 25) {
            int fi = b * 1600 + co * 25 + tid;
            // t0
            const float* tp = tile0 + (2*py)*11 + 2*px;
            float m = fmaxf(fmaxf(tp[0], tp[1]), fmaxf(tp[11], tp[12]));
            float yv = axon_step(A1, A2, y7a, y7b, m);
            y7b = y7a; y7a = yv;
            a7ch[(size_t)(2 * tt) * 51200 + fi] = yv;
            // t1
            tp = tile1 + (2*py)*11 + 2*px;
            m = fmaxf(fmaxf(tp[0], tp[1]), fmaxf(tp[11], tp[12]));
            yv = axon_step(A1, A2, y7a, y7b, m);
            y7b = y7a; y7a = yv;
            a7ch[(size_t)(2 * tt + 1) * 51200 + fi] = yv;
        }
        __syncthreads();
    }
    {   // tail t = 24
        if (tid < 121) {
            const float* a5o = a5ch + (size_t)24 * 346112;
            double a[9] = {0,0,0,0,0,0,0,0,0};
            #pragma unroll 2
            for (int ci = 0; ci < 64; ++ci) {
                const float* r = a5o + roffb + ci * 169;
                const double* wp = wbase + ci * 9;
                a[0] += (double)r[0]  * wp[0];
                a[1] += (double)r[1]  * wp[1];
                a[2] += (double)r[2]  * wp[2];
                a[3] += (double)r[13] * wp[3];
                a[4] += (double)r[14] * wp[4];
                a[5] += (double)r[15] * wp[5];
                a[6] += (double)r[26] * wp[6];
                a[7] += (double)r[27] * wp[7];
                a[8] += (double)r[28] * wp[8];
            }
            double acc = ((a[0]+a[1])+(a[2]+a[3])) + ((a[4]+a[5])+(a[6]+a[7])) + a[8];
            float cur = __fadd_rn((float)acc, bb);
            float vn = __fadd_rn(__fmul_rn(eta_m, w5s), cur);
            float sn = vn > 1.0f ? 1.0f : 0.0f;
            w5s = vn > 1.0f ? 0.0f : vn;
            float a6 = axon_step(A1, A2, y6a, y6b, sn);
            y6b = y6a; y6a = a6;
            tile0[tid] = a6;
        }
        __syncthreads();
        if (tid < 25) {
            const float* tp = tile0 + (2*py)*11 + 2*px;
            float m = fmaxf(fmaxf(tp[0], tp[1]), fmaxf(tp[11], tp[12]));
            float yv = axon_step(A1, A2, y7a, y7b, m);
            y7b = y7a; y7a = yv;
            a7ch[(size_t)24 * 51200 + b * 1600 + co * 25 + tid] = yv;
        }
    }
}

// ---- fc7g: all-t fc7+b7+LIF7+axon8 -> a8ch[25] ; 1024 blocks ----
__global__ __launch_bounds__(256) void fc7g_kernel(
        const float* __restrict__ a7ch, const float* __restrict__ w7,
        const float* __restrict__ b7, float* __restrict__ a8ch,
        float A1, float A2, float eta_m) {
    int bid = blockIdx.x;
    int b = bid & 31, ot = bid >> 5;   // 32 tiles of 16 outputs
    int tid = threadIdx.x;
    int wave = tid >> 6, lane = tid & 63;
    __shared__ float sIn[1600];
    float w7s[4] = {0.f, 0.f, 0.f, 0.f};
    float y8a[4] = {0.f, 0.f, 0.f, 0.f};
    float y8b[4] = {0.f, 0.f, 0.f, 0.f};
    for (int t = 0; t < 25; ++t) {
        const float* a7o = a7ch + (size_t)t * 51200 + b * 1600;
        for (int i = tid; i < 1600; i += 256) sIn[i] = a7o[i];
        __syncthreads();
        float* a8o = a8ch + (size_t)t * 16384;
        #pragma unroll
        for (int oi = 0; oi < 4; ++oi) {
            int o = ot * 16 + wave * 4 + oi;
            const float* wr = w7 + o * 1600;
            double acc = 0.0;
            #pragma unroll
            for (int i = 0; i < 25; ++i)
                acc += (double)sIn[i * 64 + lane] * (double)wr[i * 64 + lane];
            #pragma unroll
            for (int off = 32; off > 0; off >>= 1)
                acc += __shfl_down(acc, off);
            if (lane == 0) {
                float cur = __fadd_rn((float)acc, b7[o]);
                float vn = __fadd_rn(__fmul_rn(eta_m, w7s[oi]), cur);
                float sn = vn > 1.0f ? 1.0f : 0.0f;
                w7s[oi] = vn > 1.0f ? 0.0f : vn;
                float yv = axon_step(A1, A2, y8a[oi], y8b[oi], sn);
                y8b[oi] = y8a[oi]; y8a[oi] = yv;
                a8o[b * 512 + o] = yv;
            }
        }
        __syncthreads();
    }
}

// ---- fc8g: all-t fc8+b8+LIF8 -> out [B,10,T] ; 32 blocks ----
__global__ __launch_bounds__(64) void fc8g_kernel(
        const float* __restrict__ a8ch, const float* __restrict__ w8,
        const float* __restrict__ b8, float* __restrict__ out, float eta_m) {
    int b = blockIdx.x;
    int lane = threadIdx.x;
    float w8s[10];
    #pragma unroll
    for (int o = 0; o < 10; ++o) w8s[o] = 0.f;
    for (int t = 0; t < 25; ++t) {
        const float* sr = a8ch + (size_t)t * 16384 + b * 512;
        #pragma unroll
        for (int o = 0; o < 10; ++o) {
            const float* wr = w8 + o * 512;
            double acc = 0.0;
            #pragma unroll
            for (int i = 0; i < 8; ++i)
                acc += (double)sr[i*64+lane] * (double)wr[i*64+lane];
            #pragma unroll
            for (int off = 32; off > 0; off >>= 1)
                acc += __shfl_down(acc, off);
            if (lane == 0) {
                float cur = __fadd_rn((float)acc, b8[o]);
                float vn = __fadd_rn(__fmul_rn(eta_m, w8s[o]), cur);
                float sn = vn > 1.0f ? 1.0f : 0.0f;
                w8s[o] = vn > 1.0f ? 0.0f : vn;
                out[(b * 10 + o) * 25 + t] = sn;
            }
        }
    }
}

extern "C" void kernel_launch(void* const* d_in, const int* in_sizes, int n_in,
                              void* d_out, int out_size, void* d_ws, size_t ws_size,
                              hipStream_t stream) {
    (void)in_sizes; (void)n_in;
    const float* inp = (const float*)d_in[0];
    const float* a1w = (const float*)d_in[1];
    const float* a1b = (const float*)d_in[2];
    const float* w2  = (const float*)d_in[3];
    const float* b2  = (const float*)d_in[4];
    const float* w3  = (const float*)d_in[5];
    const float* b3  = (const float*)d_in[6];
    const float* w5  = (const float*)d_in[7];
    const float* b5  = (const float*)d_in[8];
    const float* w7  = (const float*)d_in[9];
    const float* b7  = (const float*)d_in[10];
    const float* w8  = (const float*)d_in[11];
    const float* b8  = (const float*)d_in[12];
    float* out = (float*)d_out;
    float* ws  = (float*)d_ws;

    const float em = (float)exp(-0.25);
    const float es = (float)exp(-1.0);
    const float A1 = em + es;
    const float A2 = -(em * es);

    // layout (float units); f64 arrays first for 8B alignment
    size_t off = 0;
    auto nf = [&](size_t n) { size_t o = off; off += n; return o; };
    size_t o_w2d   = nf(2*9216);
    size_t o_w3d   = nf(2*18432);
    size_t o_w5d   = nf(2*36864);
    size_t o_frame = nf(921600);
    size_t o_a2ch  = nf((size_t)25 * 921600);
    size_t o_a3ch  = nf((size_t)25 * 802816);
    size_t o_a5ch  = nf((size_t)25 * 346112);
    size_t o_a7ch  = nf((size_t)25 * 51200);
    size_t o_a8ch  = nf((size_t)25 * 16384);

    if (ws_size < off * sizeof(float)) {
        diag_kernel<<<(out_size + 255) / 256, 256, 0, stream>>>(
            out, 100.0f + (float)(ws_size >> 20), out_size);
        return;
    }

    wcvt_kernel<<<144, 256, 0, stream>>>(w2, w3, w5,
                                         (double*)(ws + o_w2d),
                                         (double*)(ws + o_w3d),
                                         (double*)(ws + o_w5d));
    ann1_kernel<<<1024, 256, 0, stream>>>(inp, a1w, a1b, ws + o_frame);
    axon2g_kernel<<<1800, 256, 0, stream>>>((const float2*)(ws + o_frame),
                                            ws + o_a2ch, A1, A2);
    conv2g_kernel<<<1024, 256, 0, stream>>>(ws + o_a2ch,
                                            (const double*)(ws + o_w2d), b2,
                                            ws + o_a3ch, A1, A2, em);
    conv3g_kernel<<<1024, 256, 0, stream>>>(ws + o_a3ch,
                                            (const double*)(ws + o_w3d), b3,
                                            ws + o_a5ch, A1, A2, em);
    conv5g_kernel<<<2048, 128, 0, stream>>>(ws + o_a5ch,
                                            (const double*)(ws + o_w5d), b5,
                                            ws + o_a7ch, A1, A2, em);
    fc7g_kernel<<<1024, 256, 0, stream>>>(ws + o_a7ch, w7, b7,
                                          ws + o_a8ch, A1, A2, em);
    fc8g_kernel<<<32, 64, 0, stream>>>(ws + o_a8ch, w8, b8, out, em);

    canary_kernel<<<1, 256, 0, stream>>>(out, out_size);
}